// Round 4
// baseline (112.385 us; speedup 1.0000x reference)
//
#include <hip/hip_runtime.h>

#define TLEN 512
#define KLEN 11
#define XPAD 256          // covers idx >= -255 (pad <= 255 worst case)
#define XTOT 1024         // max window idx for any read = 1023 (proven vs olen)
// LDS: 1024 * 16 B = 16 KiB; ws: 8 groups * 16 KiB = 128 KiB

typedef float v2f __attribute__((ext_vector_type(2)));

__device__ __forceinline__ v2f pk_fma(v2f a, v2f b, v2f c) {
    v2f d;
    asm("v_pk_fma_f32 %0, %1, %2, %3" : "=v"(d) : "v"(a), "v"(b), "v"(c));
    return d;
}

__device__ __forceinline__ float wave_max_f32(float v) {
    const int NEG_INF = 0xFF800000;
    int x = __float_as_int(v);
    int t;
    t = __builtin_amdgcn_update_dpp(NEG_INF, x, 0x111, 0xF, 0xF, false); // row_shr:1
    x = __float_as_int(fmaxf(__int_as_float(x), __int_as_float(t)));
    t = __builtin_amdgcn_update_dpp(NEG_INF, x, 0x112, 0xF, 0xF, false); // row_shr:2
    x = __float_as_int(fmaxf(__int_as_float(x), __int_as_float(t)));
    t = __builtin_amdgcn_update_dpp(NEG_INF, x, 0x114, 0xF, 0xF, false); // row_shr:4
    x = __float_as_int(fmaxf(__int_as_float(x), __int_as_float(t)));
    t = __builtin_amdgcn_update_dpp(NEG_INF, x, 0x118, 0xF, 0xF, false); // row_shr:8
    x = __float_as_int(fmaxf(__int_as_float(x), __int_as_float(t)));
    t = __builtin_amdgcn_update_dpp(NEG_INF, x, 0x142, 0xA, 0xF, false); // row_bcast:15
    x = __float_as_int(fmaxf(__int_as_float(x), __int_as_float(t)));
    t = __builtin_amdgcn_update_dpp(NEG_INF, x, 0x143, 0xC, 0xF, false); // row_bcast:31
    x = __float_as_int(fmaxf(__int_as_float(x), __int_as_float(t)));
    return __int_as_float(__builtin_amdgcn_readlane(x, 63));
}

// Build padded, 4-batch-interleaved float4 windows in ws. grid = 32 x 256.
__global__ __launch_bounds__(256) void stage_ws(const float* __restrict__ x,
                                                float4* __restrict__ ws) {
    const int t = threadIdx.x;
    const int g = blockIdx.x >> 2;        // batch group (8)
    const int seg = blockIdx.x & 3;       // quarter of the window
    const int slot = seg * 256 + t;
    float4 v = make_float4(0.f, 0.f, 0.f, 0.f);
    if (slot >= XPAD && slot < XPAD + TLEN) {
        const int pos = slot - XPAD;
        const float* xg = x + (size_t)g * 4 * TLEN;
        v = make_float4(xg[pos], xg[TLEN + pos], xg[2 * TLEN + pos], xg[3 * TLEN + pos]);
    }
    ws[(size_t)g * XTOT + slot] = v;
}

__global__ __launch_bounds__(256, 4) void rf_kernel(
    const float4* __restrict__ ws, const float* __restrict__ weight,
    const float* __restrict__ bias, const int* __restrict__ dilation,
    const int* __restrict__ padding, const int* __restrict__ out_len,
    float* __restrict__ out, int K)
{
    __shared__ float4 xs[XTOT];
    const int t = threadIdx.x;
    const float4* wsg = ws + (size_t)blockIdx.y * XTOT;

    // stage the whole padded window from ws: 4 coalesced b128 copies
    xs[t]       = wsg[t];
    xs[t + 256] = wsg[t + 256];
    xs[t + 512] = wsg[t + 512];
    xs[t + 768] = wsg[t + 768];
    __syncthreads();

    const int lane = t & 63;
    const int ks = __builtin_amdgcn_readfirstlane(blockIdx.x * 4 + (t >> 6));

    const int dil  = dilation[ks];
    const int pd   = padding[ks];
    const int olen = out_len[ks];
    const float bs = bias[ks];
    float wj[KLEN];
    v2f ww[KLEN];
    #pragma unroll
    for (int j = 0; j < KLEN; ++j) {
        wj[j] = weight[ks * KLEN + j];
        ww[j].x = wj[j]; ww[j].y = wj[j];
    }

    const int vbase = XPAD + lane - pd;   // window-slot index, hoisted VGPR

    float mx0 = -INFINITY, mx1 = -INFINITY, mx2 = -INFINITY, mx3 = -INFINITY;
    int c0 = 0, c1 = 0, c2 = 0, c3 = 0;

    #pragma unroll
    for (int i = 0; i < 8; ++i) {
        const int p0 = i * 64;
        if (p0 < olen) {                               // uniform: skip dead chunks
            v2f a0; a0.x = bs; a0.y = bs;              // bias folded into init
            v2f a1 = a0;
            #pragma unroll
            for (int j = 0; j < KLEN; ++j) {
                if (wj[j] != 0.0f) {                   // uniform: skip zero taps
                    float4 v;
                    if (j & 1) {
                        // vmem path: scalar base (SGPR) + lane offset (VGPR)
                        const float4* tp = wsg + (j * dil + p0);
                        v = tp[vbase];
                    } else {
                        // LDS path
                        v = xs[vbase + j * dil + p0];
                    }
                    v2f lo; lo.x = v.x; lo.y = v.y;
                    v2f hi; hi.x = v.z; hi.y = v.w;
                    a0 = pk_fma(ww[j], lo, a0);
                    a1 = pk_fma(ww[j], hi, a1);
                }
            }
            if (p0 + 64 <= olen) {                     // fully-valid chunk
                mx0 = fmaxf(mx0, a0.x); mx1 = fmaxf(mx1, a0.y);
                mx2 = fmaxf(mx2, a1.x); mx3 = fmaxf(mx3, a1.y);
                c0 += __popcll(__ballot(a0.x > 0.f));
                c1 += __popcll(__ballot(a0.y > 0.f));
                c2 += __popcll(__ballot(a1.x > 0.f));
                c3 += __popcll(__ballot(a1.y > 0.f));
            } else {                                   // boundary chunk
                const bool vld = lane < (olen - p0);
                mx0 = fmaxf(mx0, vld ? a0.x : -INFINITY);
                mx1 = fmaxf(mx1, vld ? a0.y : -INFINITY);
                mx2 = fmaxf(mx2, vld ? a1.x : -INFINITY);
                mx3 = fmaxf(mx3, vld ? a1.y : -INFINITY);
                c0 += __popcll(__ballot(vld && a0.x > 0.f));
                c1 += __popcll(__ballot(vld && a0.y > 0.f));
                c2 += __popcll(__ballot(vld && a1.x > 0.f));
                c3 += __popcll(__ballot(vld && a1.y > 0.f));
            }
        }
    }

    mx0 = wave_max_f32(mx0);
    mx1 = wave_max_f32(mx1);
    mx2 = wave_max_f32(mx2);
    mx3 = wave_max_f32(mx3);

    if (lane == 0) {
        const float inv = 1.0f / (float)olen;
        const size_t row = (size_t)2 * K;
        float* o = out + (size_t)blockIdx.y * 4 * row + 2 * ks;
        *(float2*)(o)           = make_float2(mx0, (float)c0 * inv);
        *(float2*)(o + row)     = make_float2(mx1, (float)c1 * inv);
        *(float2*)(o + 2 * row) = make_float2(mx2, (float)c2 * inv);
        *(float2*)(o + 3 * row) = make_float2(mx3, (float)c3 * inv);
    }
}

// ---------- fallback (R3 all-LDS) if ws_size < 128 KiB ----------
__global__ __launch_bounds__(256, 4) void rf_kernel_lds(
    const float* __restrict__ x, const float* __restrict__ weight,
    const float* __restrict__ bias, const int* __restrict__ dilation,
    const int* __restrict__ padding, const int* __restrict__ out_len,
    float* __restrict__ out, int K)
{
    __shared__ float4 xs[XTOT];
    const int t = threadIdx.x;
    const int b0 = blockIdx.y * 4;
    const float4 z4 = make_float4(0.f, 0.f, 0.f, 0.f);
    xs[t] = z4;
    xs[768 + t] = z4;
    const float* x0 = x + (size_t)b0 * TLEN;
    xs[XPAD + t]       = make_float4(x0[t], x0[TLEN + t],
                                     x0[2 * TLEN + t], x0[3 * TLEN + t]);
    xs[XPAD + 256 + t] = make_float4(x0[256 + t], x0[TLEN + 256 + t],
                                     x0[2 * TLEN + 256 + t], x0[3 * TLEN + 256 + t]);
    __syncthreads();

    const int lane = t & 63;
    const int ks = __builtin_amdgcn_readfirstlane(blockIdx.x * 4 + (t >> 6));
    const int dil  = dilation[ks];
    const int pd   = padding[ks];
    const int olen = out_len[ks];
    const float bs = bias[ks];
    float wj[KLEN];
    #pragma unroll
    for (int j = 0; j < KLEN; ++j) wj[j] = weight[ks * KLEN + j];
    const int base = XPAD + lane - pd;

    float4 mx = make_float4(-INFINITY, -INFINITY, -INFINITY, -INFINITY);
    int c0 = 0, c1 = 0, c2 = 0, c3 = 0;
    #pragma unroll
    for (int i = 0; i < 8; ++i) {
        const int p0 = i * 64;
        if (p0 < olen) {
            float4 a = z4;
            #pragma unroll
            for (int j = 0; j < KLEN; ++j) {
                if (wj[j] != 0.0f) {
                    const float4 v = xs[base + j * dil + p0];
                    a.x = fmaf(wj[j], v.x, a.x);
                    a.y = fmaf(wj[j], v.y, a.y);
                    a.z = fmaf(wj[j], v.z, a.z);
                    a.w = fmaf(wj[j], v.w, a.w);
                }
            }
            a.x += bs; a.y += bs; a.z += bs; a.w += bs;
            if (p0 + 64 <= olen) {
                mx.x = fmaxf(mx.x, a.x); mx.y = fmaxf(mx.y, a.y);
                mx.z = fmaxf(mx.z, a.z); mx.w = fmaxf(mx.w, a.w);
                c0 += __popcll(__ballot(a.x > 0.f));
                c1 += __popcll(__ballot(a.y > 0.f));
                c2 += __popcll(__ballot(a.z > 0.f));
                c3 += __popcll(__ballot(a.w > 0.f));
            } else {
                const bool vld = lane < (olen - p0);
                mx.x = fmaxf(mx.x, vld ? a.x : -INFINITY);
                mx.y = fmaxf(mx.y, vld ? a.y : -INFINITY);
                mx.z = fmaxf(mx.z, vld ? a.z : -INFINITY);
                mx.w = fmaxf(mx.w, vld ? a.w : -INFINITY);
                c0 += __popcll(__ballot(vld && a.x > 0.f));
                c1 += __popcll(__ballot(vld && a.y > 0.f));
                c2 += __popcll(__ballot(vld && a.z > 0.f));
                c3 += __popcll(__ballot(vld && a.w > 0.f));
            }
        }
    }
    mx.x = wave_max_f32(mx.x);
    mx.y = wave_max_f32(mx.y);
    mx.z = wave_max_f32(mx.z);
    mx.w = wave_max_f32(mx.w);
    if (lane == 0) {
        const float inv = 1.0f / (float)olen;
        const size_t row = (size_t)2 * K;
        float* o = out + (size_t)b0 * row + 2 * ks;
        *(float2*)(o)           = make_float2(mx.x, (float)c0 * inv);
        *(float2*)(o + row)     = make_float2(mx.y, (float)c1 * inv);
        *(float2*)(o + 2 * row) = make_float2(mx.z, (float)c2 * inv);
        *(float2*)(o + 3 * row) = make_float2(mx.w, (float)c3 * inv);
    }
}

extern "C" void kernel_launch(void* const* d_in, const int* in_sizes, int n_in,
                              void* d_out, int out_size, void* d_ws, size_t ws_size,
                              hipStream_t stream) {
    const float* x    = (const float*)d_in[0];
    const float* w    = (const float*)d_in[1];
    const float* bias = (const float*)d_in[2];
    const int* dil    = (const int*)d_in[3];
    const int* pad    = (const int*)d_in[4];
    const int* olen   = (const int*)d_in[5];
    float* out        = (float*)d_out;

    const int K = in_sizes[2];          // 4096
    const int B = in_sizes[0] / TLEN;   // 32
    const size_t ws_need = (size_t)(B / 4) * XTOT * sizeof(float4);  // 128 KiB

    if (ws_size >= ws_need) {
        float4* ws = (float4*)d_ws;
        stage_ws<<<dim3((B / 4) * 4), 256, 0, stream>>>(x, ws);
        dim3 grid(K / 4, B / 4);
        rf_kernel<<<grid, 256, 0, stream>>>(ws, w, bias, dil, pad, olen, out, K);
    } else {
        dim3 grid(K / 4, B / 4);
        rf_kernel_lds<<<grid, 256, 0, stream>>>(x, w, bias, dil, pad, olen, out, K);
    }
}

// Round 5
// 104.191 us; speedup vs baseline: 1.0786x; 1.0786x over previous
//
#include <hip/hip_runtime.h>
#include <hip/hip_fp16.h>

#define TLEN 512
#define KLEN 11
#define XPAD 256          // covers slot >= 1 for pad <= 255
#define XTOT 1024         // 1024 slots * 16 B = 16 KiB LDS (8 batches fp16 per slot)

// acc (f32) += w (f32) * lo/hi-half(h) (f16)
#define MIX_LO(acc, w, h) \
    asm("v_fma_mix_f32 %0, %1, %2, %0 op_sel_hi:[0,1,0]" : "+v"(acc) : "v"(w), "v"(h))
#define MIX_HI(acc, w, h) \
    asm("v_fma_mix_f32 %0, %1, %2, %0 op_sel:[0,1,0] op_sel_hi:[0,1,0]" : "+v"(acc) : "v"(w), "v"(h))

__device__ __forceinline__ float wave_max_f32(float v) {
    const int NEG_INF = 0xFF800000;
    int x = __float_as_int(v);
    int t;
    t = __builtin_amdgcn_update_dpp(NEG_INF, x, 0x111, 0xF, 0xF, false); // row_shr:1
    x = __float_as_int(fmaxf(__int_as_float(x), __int_as_float(t)));
    t = __builtin_amdgcn_update_dpp(NEG_INF, x, 0x112, 0xF, 0xF, false); // row_shr:2
    x = __float_as_int(fmaxf(__int_as_float(x), __int_as_float(t)));
    t = __builtin_amdgcn_update_dpp(NEG_INF, x, 0x114, 0xF, 0xF, false); // row_shr:4
    x = __float_as_int(fmaxf(__int_as_float(x), __int_as_float(t)));
    t = __builtin_amdgcn_update_dpp(NEG_INF, x, 0x118, 0xF, 0xF, false); // row_shr:8
    x = __float_as_int(fmaxf(__int_as_float(x), __int_as_float(t)));
    t = __builtin_amdgcn_update_dpp(NEG_INF, x, 0x142, 0xA, 0xF, false); // row_bcast:15
    x = __float_as_int(fmaxf(__int_as_float(x), __int_as_float(t)));
    t = __builtin_amdgcn_update_dpp(NEG_INF, x, 0x143, 0xC, 0xF, false); // row_bcast:31
    x = __float_as_int(fmaxf(__int_as_float(x), __int_as_float(t)));
    return __int_as_float(__builtin_amdgcn_readlane(x, 63));
}

// Pre-kernel: build zero-padded, 8-batch-interleaved fp16 windows in ws.
// grid = (B/8)*4 blocks of 256. ws layout: [group][slot] of uint4 (8 halves).
__global__ __launch_bounds__(256) void stage_ws_h(const float* __restrict__ x,
                                                  uint4* __restrict__ ws) {
    const int t = threadIdx.x;
    const int g = blockIdx.x >> 2;
    const int seg = blockIdx.x & 3;
    const int slot = seg * 256 + t;
    uint4 v = make_uint4(0u, 0u, 0u, 0u);
    if (slot >= XPAD && slot < XPAD + TLEN) {
        const int pos = slot - XPAD;
        const float* xg = x + (size_t)g * 8 * TLEN;
        unsigned h[8];
        #pragma unroll
        for (int q = 0; q < 8; ++q)
            h[q] = (unsigned)__half_as_ushort(__float2half(xg[q * TLEN + pos]));
        v.x = h[0] | (h[1] << 16);
        v.y = h[2] | (h[3] << 16);
        v.z = h[4] | (h[5] << 16);
        v.w = h[6] | (h[7] << 16);
    }
    ws[(size_t)g * XTOT + slot] = v;
}

__global__ __launch_bounds__(256, 4) void rf_kernel_h(
    const uint4* __restrict__ ws, const float* __restrict__ weight,
    const float* __restrict__ bias, const int* __restrict__ dilation,
    const int* __restrict__ padding, const int* __restrict__ out_len,
    float* __restrict__ out, int K)
{
    __shared__ uint4 xs[XTOT];
    const int t = threadIdx.x;
    const uint4* wsg = ws + (size_t)blockIdx.y * XTOT;

    xs[t]       = wsg[t];
    xs[t + 256] = wsg[t + 256];
    xs[t + 512] = wsg[t + 512];
    xs[t + 768] = wsg[t + 768];
    __syncthreads();

    const int lane = t & 63;
    const int ks = __builtin_amdgcn_readfirstlane(blockIdx.x * 4 + (t >> 6));

    const int dil  = dilation[ks];
    const int pd   = padding[ks];
    const int olen = out_len[ks];
    const float bs = bias[ks];
    float wj[KLEN];
    #pragma unroll
    for (int j = 0; j < KLEN; ++j) wj[j] = weight[ks * KLEN + j];

    // per-tap LDS base pointers hoisted: inner ds_read uses imm offset only
    const int vbase = XPAD + lane - pd;
    const uint4* xp[KLEN];
    #pragma unroll
    for (int j = 0; j < KLEN; ++j) xp[j] = xs + (vbase + j * dil);

    float mx[8];
    int cnt[8];
    #pragma unroll
    for (int q = 0; q < 8; ++q) { mx[q] = -INFINITY; cnt[q] = 0; }

    #pragma unroll
    for (int i = 0; i < 8; ++i) {
        const int p0 = i * 64;
        if (p0 < olen) {                               // uniform: skip dead chunks
            float a[8];
            #pragma unroll
            for (int q = 0; q < 8; ++q) a[q] = bs;     // bias folded into init
            #pragma unroll
            for (int j = 0; j < KLEN; ++j) {
                if (wj[j] != 0.0f) {                   // uniform: skip zero taps
                    const uint4 r = xp[j][p0];         // ds_read_b128, imm p0*16
                    MIX_LO(a[0], wj[j], r.x); MIX_HI(a[1], wj[j], r.x);
                    MIX_LO(a[2], wj[j], r.y); MIX_HI(a[3], wj[j], r.y);
                    MIX_LO(a[4], wj[j], r.z); MIX_HI(a[5], wj[j], r.z);
                    MIX_LO(a[6], wj[j], r.w); MIX_HI(a[7], wj[j], r.w);
                }
            }
            if (p0 + 64 <= olen) {                     // fully-valid chunk
                #pragma unroll
                for (int q = 0; q < 8; ++q) {
                    mx[q] = fmaxf(mx[q], a[q]);
                    cnt[q] += __popcll(__ballot(a[q] > 0.f));
                }
            } else {                                   // boundary chunk
                const bool vld = lane < (olen - p0);
                #pragma unroll
                for (int q = 0; q < 8; ++q) {
                    mx[q] = fmaxf(mx[q], vld ? a[q] : -INFINITY);
                    cnt[q] += __popcll(__ballot(vld && a[q] > 0.f));
                }
            }
        }
    }

    #pragma unroll
    for (int q = 0; q < 8; ++q) mx[q] = wave_max_f32(mx[q]);

    if (lane == 0) {
        const float inv = 1.0f / (float)olen;
        const size_t row = (size_t)2 * K;
        float* o = out + (size_t)blockIdx.y * 8 * row + 2 * ks;
        #pragma unroll
        for (int q = 0; q < 8; ++q)
            *(float2*)(o + q * row) = make_float2(mx[q], (float)cnt[q] * inv);
    }
}

// ---------- fallback (R3 all-LDS fp32, known-good) ----------
__global__ __launch_bounds__(256, 4) void rf_kernel_lds(
    const float* __restrict__ x, const float* __restrict__ weight,
    const float* __restrict__ bias, const int* __restrict__ dilation,
    const int* __restrict__ padding, const int* __restrict__ out_len,
    float* __restrict__ out, int K)
{
    __shared__ float4 xs[XTOT];
    const int t = threadIdx.x;
    const int b0 = blockIdx.y * 4;
    const float4 z4 = make_float4(0.f, 0.f, 0.f, 0.f);
    xs[t] = z4;
    xs[768 + t] = z4;
    const float* x0 = x + (size_t)b0 * TLEN;
    xs[XPAD + t]       = make_float4(x0[t], x0[TLEN + t],
                                     x0[2 * TLEN + t], x0[3 * TLEN + t]);
    xs[XPAD + 256 + t] = make_float4(x0[256 + t], x0[TLEN + 256 + t],
                                     x0[2 * TLEN + 256 + t], x0[3 * TLEN + 256 + t]);
    __syncthreads();

    const int lane = t & 63;
    const int ks = __builtin_amdgcn_readfirstlane(blockIdx.x * 4 + (t >> 6));
    const int dil  = dilation[ks];
    const int pd   = padding[ks];
    const int olen = out_len[ks];
    const float bs = bias[ks];
    float wj[KLEN];
    #pragma unroll
    for (int j = 0; j < KLEN; ++j) wj[j] = weight[ks * KLEN + j];
    const int base = XPAD + lane - pd;

    float4 mx = make_float4(-INFINITY, -INFINITY, -INFINITY, -INFINITY);
    int c0 = 0, c1 = 0, c2 = 0, c3 = 0;
    #pragma unroll
    for (int i = 0; i < 8; ++i) {
        const int p0 = i * 64;
        if (p0 < olen) {
            float4 a = z4;
            #pragma unroll
            for (int j = 0; j < KLEN; ++j) {
                if (wj[j] != 0.0f) {
                    const float4 v = xs[base + j * dil + p0];
                    a.x = fmaf(wj[j], v.x, a.x);
                    a.y = fmaf(wj[j], v.y, a.y);
                    a.z = fmaf(wj[j], v.z, a.z);
                    a.w = fmaf(wj[j], v.w, a.w);
                }
            }
            a.x += bs; a.y += bs; a.z += bs; a.w += bs;
            if (p0 + 64 <= olen) {
                mx.x = fmaxf(mx.x, a.x); mx.y = fmaxf(mx.y, a.y);
                mx.z = fmaxf(mx.z, a.z); mx.w = fmaxf(mx.w, a.w);
                c0 += __popcll(__ballot(a.x > 0.f));
                c1 += __popcll(__ballot(a.y > 0.f));
                c2 += __popcll(__ballot(a.z > 0.f));
                c3 += __popcll(__ballot(a.w > 0.f));
            } else {
                const bool vld = lane < (olen - p0);
                mx.x = fmaxf(mx.x, vld ? a.x : -INFINITY);
                mx.y = fmaxf(mx.y, vld ? a.y : -INFINITY);
                mx.z = fmaxf(mx.z, vld ? a.z : -INFINITY);
                mx.w = fmaxf(mx.w, vld ? a.w : -INFINITY);
                c0 += __popcll(__ballot(vld && a.x > 0.f));
                c1 += __popcll(__ballot(vld && a.y > 0.f));
                c2 += __popcll(__ballot(vld && a.z > 0.f));
                c3 += __popcll(__ballot(vld && a.w > 0.f));
            }
        }
    }
    mx.x = wave_max_f32(mx.x);
    mx.y = wave_max_f32(mx.y);
    mx.z = wave_max_f32(mx.z);
    mx.w = wave_max_f32(mx.w);
    if (lane == 0) {
        const float inv = 1.0f / (float)olen;
        const size_t row = (size_t)2 * K;
        float* o = out + (size_t)b0 * row + 2 * ks;
        *(float2*)(o)           = make_float2(mx.x, (float)c0 * inv);
        *(float2*)(o + row)     = make_float2(mx.y, (float)c1 * inv);
        *(float2*)(o + 2 * row) = make_float2(mx.z, (float)c2 * inv);
        *(float2*)(o + 3 * row) = make_float2(mx.w, (float)c3 * inv);
    }
}

extern "C" void kernel_launch(void* const* d_in, const int* in_sizes, int n_in,
                              void* d_out, int out_size, void* d_ws, size_t ws_size,
                              hipStream_t stream) {
    const float* x    = (const float*)d_in[0];
    const float* w    = (const float*)d_in[1];
    const float* bias = (const float*)d_in[2];
    const int* dil    = (const int*)d_in[3];
    const int* pad    = (const int*)d_in[4];
    const int* olen   = (const int*)d_in[5];
    float* out        = (float*)d_out;

    const int K = in_sizes[2];          // 4096
    const int B = in_sizes[0] / TLEN;   // 32
    const int G = B / 8;                // 4 batch groups
    const size_t ws_need = (size_t)G * XTOT * sizeof(uint4);  // 64 KiB

    if (ws_size >= ws_need && (B % 8) == 0) {
        uint4* ws = (uint4*)d_ws;
        stage_ws_h<<<dim3(G * 4), 256, 0, stream>>>(x, ws);
        dim3 grid(K / 4, G);            // 1024 x 4 blocks, 4 waves each
        rf_kernel_h<<<grid, 256, 0, stream>>>(ws, w, bias, dil, pad, olen, out, K);
    } else {
        dim3 grid(K / 4, B / 4);
        rf_kernel_lds<<<grid, 256, 0, stream>>>(x, w, bias, dil, pad, olen, out, K);
    }
}

// Round 6
// 98.618 us; speedup vs baseline: 1.1396x; 1.0565x over previous
//
#include <hip/hip_runtime.h>
#include <hip/hip_fp16.h>

#define TLEN 512
#define KLEN 11
#define XPAD 256          // covers slot >= 1 for pad <= 255
#define XTOT 1024         // 16 KiB LDS: 1024 slots x 8 fp16 (8 batches interleaved)

__device__ __forceinline__ __half2 pk_max_h2(__half2 a, __half2 b) {
    __half2 d;
    asm("v_pk_max_f16 %0, %1, %2" : "=v"(d) : "v"(a), "v"(b));
    return d;
}

__device__ __forceinline__ float wave_max_f32(float v) {
    const int NEG_INF = 0xFF800000;
    int x = __float_as_int(v);
    int t;
    t = __builtin_amdgcn_update_dpp(NEG_INF, x, 0x111, 0xF, 0xF, false);
    x = __float_as_int(fmaxf(__int_as_float(x), __int_as_float(t)));
    t = __builtin_amdgcn_update_dpp(NEG_INF, x, 0x112, 0xF, 0xF, false);
    x = __float_as_int(fmaxf(__int_as_float(x), __int_as_float(t)));
    t = __builtin_amdgcn_update_dpp(NEG_INF, x, 0x114, 0xF, 0xF, false);
    x = __float_as_int(fmaxf(__int_as_float(x), __int_as_float(t)));
    t = __builtin_amdgcn_update_dpp(NEG_INF, x, 0x118, 0xF, 0xF, false);
    x = __float_as_int(fmaxf(__int_as_float(x), __int_as_float(t)));
    t = __builtin_amdgcn_update_dpp(NEG_INF, x, 0x142, 0xA, 0xF, false);
    x = __float_as_int(fmaxf(__int_as_float(x), __int_as_float(t)));
    t = __builtin_amdgcn_update_dpp(NEG_INF, x, 0x143, 0xC, 0xF, false);
    x = __float_as_int(fmaxf(__int_as_float(x), __int_as_float(t)));
    return __int_as_float(__builtin_amdgcn_readlane(x, 63));
}

__device__ __forceinline__ float wave_sum_f32(float v) {
    int x = __float_as_int(v);
    int t;
    t = __builtin_amdgcn_update_dpp(0, x, 0x111, 0xF, 0xF, false);
    x = __float_as_int(__int_as_float(x) + __int_as_float(t));
    t = __builtin_amdgcn_update_dpp(0, x, 0x112, 0xF, 0xF, false);
    x = __float_as_int(__int_as_float(x) + __int_as_float(t));
    t = __builtin_amdgcn_update_dpp(0, x, 0x114, 0xF, 0xF, false);
    x = __float_as_int(__int_as_float(x) + __int_as_float(t));
    t = __builtin_amdgcn_update_dpp(0, x, 0x118, 0xF, 0xF, false);
    x = __float_as_int(__int_as_float(x) + __int_as_float(t));
    t = __builtin_amdgcn_update_dpp(0, x, 0x142, 0xA, 0xF, false);
    x = __float_as_int(__int_as_float(x) + __int_as_float(t));
    t = __builtin_amdgcn_update_dpp(0, x, 0x143, 0xC, 0xF, false);
    x = __float_as_int(__int_as_float(x) + __int_as_float(t));
    return __int_as_float(__builtin_amdgcn_readlane(x, 63));
}

// Pre-kernel: zero-padded, 8-batch-interleaved fp16 windows in ws.
__global__ __launch_bounds__(256) void stage_ws_h(const float* __restrict__ x,
                                                  uint4* __restrict__ ws) {
    const int t = threadIdx.x;
    const int g = blockIdx.x >> 2;
    const int seg = blockIdx.x & 3;
    const int slot = seg * 256 + t;
    uint4 v = make_uint4(0u, 0u, 0u, 0u);
    if (slot >= XPAD && slot < XPAD + TLEN) {
        const int pos = slot - XPAD;
        const float* xg = x + (size_t)g * 8 * TLEN;
        unsigned h[8];
        #pragma unroll
        for (int q = 0; q < 8; ++q)
            h[q] = (unsigned)__half_as_ushort(__float2half(xg[q * TLEN + pos]));
        v.x = h[0] | (h[1] << 16);
        v.y = h[2] | (h[3] << 16);
        v.z = h[4] | (h[5] << 16);
        v.w = h[6] | (h[7] << 16);
    }
    ws[(size_t)g * XTOT + slot] = v;
}

__global__ __launch_bounds__(256, 4) void rf_kernel_h2(
    const uint4* __restrict__ ws, const float* __restrict__ weight,
    const float* __restrict__ bias, const int* __restrict__ dilation,
    const int* __restrict__ padding, const int* __restrict__ out_len,
    float* __restrict__ out, int K)
{
    __shared__ uint4 xs[XTOT];
    const int t = threadIdx.x;
    const uint4* wsg = ws + (size_t)blockIdx.y * XTOT;

    xs[t]       = wsg[t];
    xs[t + 256] = wsg[t + 256];
    xs[t + 512] = wsg[t + 512];
    xs[t + 768] = wsg[t + 768];
    __syncthreads();

    const int lane = t & 63;
    const int ks = __builtin_amdgcn_readfirstlane(blockIdx.x * 4 + (t >> 6));

    const int dil  = dilation[ks];
    const int pd   = padding[ks];
    const int olen = out_len[ks];
    float wjf[KLEN];
    __half2 w2[KLEN];
    #pragma unroll
    for (int j = 0; j < KLEN; ++j) {
        wjf[j] = weight[ks * KLEN + j];
        w2[j] = __float2half2_rn(wjf[j]);
    }
    const __half2 bias2 = __float2half2_rn(bias[ks]);
    const unsigned NEGINF2 = 0xFC00FC00u;
    const __half2 zero2 = __float2half2_rn(0.0f);

    const int vbase = XPAD + lane - pd;

    __half2 mx[4], cf[4];
    #pragma unroll
    for (int q = 0; q < 4; ++q) {
        unsigned n = NEGINF2;
        __builtin_memcpy(&mx[q], &n, 4);
        cf[q] = zero2;
    }

    #pragma unroll
    for (int i = 0; i < 8; ++i) {
        const int p0 = i * 64;
        if (p0 < olen) {                               // uniform: skip dead chunks
            __half2 aA[4], aB[4];
            #pragma unroll
            for (int q = 0; q < 4; ++q) { aA[q] = bias2; aB[q] = zero2; }
            #pragma unroll
            for (int j = 0; j < KLEN; ++j) {
                if (wjf[j] != 0.0f) {                  // uniform: skip zero taps
                    const uint4 r = xs[vbase + j * dil + p0];
                    __half2 h0, h1, h2, h3;
                    __builtin_memcpy(&h0, &r.x, 4);
                    __builtin_memcpy(&h1, &r.y, 4);
                    __builtin_memcpy(&h2, &r.z, 4);
                    __builtin_memcpy(&h3, &r.w, 4);
                    if (j & 1) {                       // parity-split chains
                        aB[0] = __hfma2(w2[j], h0, aB[0]);
                        aB[1] = __hfma2(w2[j], h1, aB[1]);
                        aB[2] = __hfma2(w2[j], h2, aB[2]);
                        aB[3] = __hfma2(w2[j], h3, aB[3]);
                    } else {
                        aA[0] = __hfma2(w2[j], h0, aA[0]);
                        aA[1] = __hfma2(w2[j], h1, aA[1]);
                        aA[2] = __hfma2(w2[j], h2, aA[2]);
                        aA[3] = __hfma2(w2[j], h3, aA[3]);
                    }
                }
            }
            if (p0 + 64 <= olen) {                     // fully-valid chunk
                #pragma unroll
                for (int q = 0; q < 4; ++q) {
                    const __half2 c = __hadd2(aA[q], aB[q]);
                    mx[q] = pk_max_h2(mx[q], c);
                    cf[q] = __hadd2(cf[q], __hgt2(c, zero2));
                }
            } else {                                   // boundary chunk
                const bool vld = lane < (olen - p0);
                #pragma unroll
                for (int q = 0; q < 4; ++q) {
                    __half2 c = __hadd2(aA[q], aB[q]);
                    unsigned cu;
                    __builtin_memcpy(&cu, &c, 4);
                    cu = vld ? cu : NEGINF2;
                    __half2 cm;
                    __builtin_memcpy(&cm, &cu, 4);
                    mx[q] = pk_max_h2(mx[q], cm);
                    __half2 ones = __hgt2(c, zero2);
                    ones = vld ? ones : zero2;
                    cf[q] = __hadd2(cf[q], ones);
                }
            }
        }
    }

    // unpack to f32, wave-reduce
    float m[8], c[8];
    #pragma unroll
    for (int q = 0; q < 4; ++q) {
        m[2 * q]     = __low2float(mx[q]);
        m[2 * q + 1] = __high2float(mx[q]);
        c[2 * q]     = __low2float(cf[q]);
        c[2 * q + 1] = __high2float(cf[q]);
    }
    #pragma unroll
    for (int q = 0; q < 8; ++q) {
        m[q] = wave_max_f32(m[q]);
        c[q] = wave_sum_f32(c[q]);
    }

    if (lane == 0) {
        const float inv = 1.0f / (float)olen;
        const size_t row = (size_t)2 * K;
        float* o = out + (size_t)blockIdx.y * 8 * row + 2 * ks;
        #pragma unroll
        for (int q = 0; q < 8; ++q)
            *(float2*)(o + q * row) = make_float2(m[q], c[q] * inv);
    }
}

// ---------- fallback (R3 all-LDS fp32, known-good) ----------
__global__ __launch_bounds__(256, 4) void rf_kernel_lds(
    const float* __restrict__ x, const float* __restrict__ weight,
    const float* __restrict__ bias, const int* __restrict__ dilation,
    const int* __restrict__ padding, const int* __restrict__ out_len,
    float* __restrict__ out, int K)
{
    __shared__ float4 xs[XTOT];
    const int t = threadIdx.x;
    const int b0 = blockIdx.y * 4;
    const float4 z4 = make_float4(0.f, 0.f, 0.f, 0.f);
    xs[t] = z4;
    xs[768 + t] = z4;
    const float* x0 = x + (size_t)b0 * TLEN;
    xs[XPAD + t]       = make_float4(x0[t], x0[TLEN + t],
                                     x0[2 * TLEN + t], x0[3 * TLEN + t]);
    xs[XPAD + 256 + t] = make_float4(x0[256 + t], x0[TLEN + 256 + t],
                                     x0[2 * TLEN + 256 + t], x0[3 * TLEN + 256 + t]);
    __syncthreads();

    const int lane = t & 63;
    const int ks = __builtin_amdgcn_readfirstlane(blockIdx.x * 4 + (t >> 6));
    const int dil  = dilation[ks];
    const int pd   = padding[ks];
    const int olen = out_len[ks];
    const float bs = bias[ks];
    float wj[KLEN];
    #pragma unroll
    for (int j = 0; j < KLEN; ++j) wj[j] = weight[ks * KLEN + j];
    const int base = XPAD + lane - pd;

    float4 mx = make_float4(-INFINITY, -INFINITY, -INFINITY, -INFINITY);
    int c0 = 0, c1 = 0, c2 = 0, c3 = 0;
    #pragma unroll
    for (int i = 0; i < 8; ++i) {
        const int p0 = i * 64;
        if (p0 < olen) {
            float4 a = z4;
            #pragma unroll
            for (int j = 0; j < KLEN; ++j) {
                if (wj[j] != 0.0f) {
                    const float4 v = xs[base + j * dil + p0];
                    a.x = fmaf(wj[j], v.x, a.x);
                    a.y = fmaf(wj[j], v.y, a.y);
                    a.z = fmaf(wj[j], v.z, a.z);
                    a.w = fmaf(wj[j], v.w, a.w);
                }
            }
            a.x += bs; a.y += bs; a.z += bs; a.w += bs;
            if (p0 + 64 <= olen) {
                mx.x = fmaxf(mx.x, a.x); mx.y = fmaxf(mx.y, a.y);
                mx.z = fmaxf(mx.z, a.z); mx.w = fmaxf(mx.w, a.w);
                c0 += __popcll(__ballot(a.x > 0.f));
                c1 += __popcll(__ballot(a.y > 0.f));
                c2 += __popcll(__ballot(a.z > 0.f));
                c3 += __popcll(__ballot(a.w > 0.f));
            } else {
                const bool vld = lane < (olen - p0);
                mx.x = fmaxf(mx.x, vld ? a.x : -INFINITY);
                mx.y = fmaxf(mx.y, vld ? a.y : -INFINITY);
                mx.z = fmaxf(mx.z, vld ? a.z : -INFINITY);
                mx.w = fmaxf(mx.w, vld ? a.w : -INFINITY);
                c0 += __popcll(__ballot(vld && a.x > 0.f));
                c1 += __popcll(__ballot(vld && a.y > 0.f));
                c2 += __popcll(__ballot(vld && a.z > 0.f));
                c3 += __popcll(__ballot(vld && a.w > 0.f));
            }
        }
    }
    mx.x = wave_max_f32(mx.x);
    mx.y = wave_max_f32(mx.y);
    mx.z = wave_max_f32(mx.z);
    mx.w = wave_max_f32(mx.w);
    if (lane == 0) {
        const float inv = 1.0f / (float)olen;
        const size_t row = (size_t)2 * K;
        float* o = out + (size_t)b0 * row + 2 * ks;
        *(float2*)(o)           = make_float2(mx.x, (float)c0 * inv);
        *(float2*)(o + row)     = make_float2(mx.y, (float)c1 * inv);
        *(float2*)(o + 2 * row) = make_float2(mx.z, (float)c2 * inv);
        *(float2*)(o + 3 * row) = make_float2(mx.w, (float)c3 * inv);
    }
}

extern "C" void kernel_launch(void* const* d_in, const int* in_sizes, int n_in,
                              void* d_out, int out_size, void* d_ws, size_t ws_size,
                              hipStream_t stream) {
    const float* x    = (const float*)d_in[0];
    const float* w    = (const float*)d_in[1];
    const float* bias = (const float*)d_in[2];
    const int* dil    = (const int*)d_in[3];
    const int* pad    = (const int*)d_in[4];
    const int* olen   = (const int*)d_in[5];
    float* out        = (float*)d_out;

    const int K = in_sizes[2];          // 4096
    const int B = in_sizes[0] / TLEN;   // 32
    const int G = B / 8;                // 4 batch groups
    const size_t ws_need = (size_t)G * XTOT * sizeof(uint4);  // 64 KiB

    if (ws_size >= ws_need && (B % 8) == 0) {
        uint4* ws = (uint4*)d_ws;
        stage_ws_h<<<dim3(G * 4), 256, 0, stream>>>(x, ws);
        dim3 grid(K / 4, G);            // 1024 x 4 blocks, 4 waves each
        rf_kernel_h2<<<grid, 256, 0, stream>>>(ws, w, bias, dil, pad, olen, out, K);
    } else {
        dim3 grid(K / 4, B / 4);
        rf_kernel_lds<<<grid, 256, 0, stream>>>(x, w, bias, dil, pad, olen, out, K);
    }
}

// Round 7
// 89.077 us; speedup vs baseline: 1.2617x; 1.1071x over previous
//
#include <hip/hip_runtime.h>
#include <hip/hip_fp16.h>

#define TLEN 512
#define KLEN 11
#define XPAD 256          // covers slot >= 1 for pad <= 255
#define XTOT 1024         // 16 KiB LDS: 1024 slots x 8 fp16 (8 batches interleaved)
#define NEGINF2 0xFC00FC00u

__device__ __forceinline__ unsigned pkmax_u(unsigned a, unsigned b) {
    unsigned d;
    asm("v_pk_max_f16 %0, %1, %2" : "=v"(d) : "v"(a), "v"(b));
    return d;
}
__device__ __forceinline__ unsigned pkadd_u(unsigned a, unsigned b) {
    unsigned d;
    asm("v_pk_add_f16 %0, %1, %2" : "=v"(d) : "v"(a), "v"(b));
    return d;
}

__device__ __forceinline__ unsigned wred_pkmax(unsigned x) {
    unsigned t;
    t = __builtin_amdgcn_update_dpp((int)NEGINF2, (int)x, 0x111, 0xF, 0xF, false);
    x = pkmax_u(x, t);
    t = __builtin_amdgcn_update_dpp((int)NEGINF2, (int)x, 0x112, 0xF, 0xF, false);
    x = pkmax_u(x, t);
    t = __builtin_amdgcn_update_dpp((int)NEGINF2, (int)x, 0x114, 0xF, 0xF, false);
    x = pkmax_u(x, t);
    t = __builtin_amdgcn_update_dpp((int)NEGINF2, (int)x, 0x118, 0xF, 0xF, false);
    x = pkmax_u(x, t);
    t = __builtin_amdgcn_update_dpp((int)NEGINF2, (int)x, 0x142, 0xA, 0xF, false);
    x = pkmax_u(x, t);
    t = __builtin_amdgcn_update_dpp((int)NEGINF2, (int)x, 0x143, 0xC, 0xF, false);
    x = pkmax_u(x, t);
    return (unsigned)__builtin_amdgcn_readlane((int)x, 63);
}
__device__ __forceinline__ unsigned wred_pkadd(unsigned x) {
    unsigned t;
    t = __builtin_amdgcn_update_dpp(0, (int)x, 0x111, 0xF, 0xF, false);
    x = pkadd_u(x, t);
    t = __builtin_amdgcn_update_dpp(0, (int)x, 0x112, 0xF, 0xF, false);
    x = pkadd_u(x, t);
    t = __builtin_amdgcn_update_dpp(0, (int)x, 0x114, 0xF, 0xF, false);
    x = pkadd_u(x, t);
    t = __builtin_amdgcn_update_dpp(0, (int)x, 0x118, 0xF, 0xF, false);
    x = pkadd_u(x, t);
    t = __builtin_amdgcn_update_dpp(0, (int)x, 0x142, 0xA, 0xF, false);
    x = pkadd_u(x, t);
    t = __builtin_amdgcn_update_dpp(0, (int)x, 0x143, 0xC, 0xF, false);
    x = pkadd_u(x, t);
    return (unsigned)__builtin_amdgcn_readlane((int)x, 63);
}

__device__ __forceinline__ __half2 as_h2(unsigned u) {
    __half2 h; __builtin_memcpy(&h, &u, 4); return h;
}
__device__ __forceinline__ unsigned as_u(__half2 h) {
    unsigned u; __builtin_memcpy(&u, &h, 4); return u;
}

// Pre-kernel: zero-padded, 8-batch-interleaved fp16 windows in ws.
__global__ __launch_bounds__(256) void stage_ws_h(const float* __restrict__ x,
                                                  uint4* __restrict__ ws) {
    const int t = threadIdx.x;
    const int g = blockIdx.x >> 2;
    const int seg = blockIdx.x & 3;
    const int slot = seg * 256 + t;
    uint4 v = make_uint4(0u, 0u, 0u, 0u);
    if (slot >= XPAD && slot < XPAD + TLEN) {
        const int pos = slot - XPAD;
        const float* xg = x + (size_t)g * 8 * TLEN;
        unsigned h[8];
        #pragma unroll
        for (int q = 0; q < 8; ++q)
            h[q] = (unsigned)__half_as_ushort(__float2half(xg[q * TLEN + pos]));
        v.x = h[0] | (h[1] << 16);
        v.y = h[2] | (h[3] << 16);
        v.z = h[4] | (h[5] << 16);
        v.w = h[6] | (h[7] << 16);
    }
    ws[(size_t)g * XTOT + slot] = v;
}

// taps-outer / chunks-inner: per tap ONE address, 8 independent ds_read_b128
// at immediate offsets; persistent per-chunk half2 accumulators (32 VGPRs).
__global__ __launch_bounds__(256, 4) void rf_kernel_h3(
    const uint4* __restrict__ ws, const float* __restrict__ weight,
    const float* __restrict__ bias, const int* __restrict__ dilation,
    const int* __restrict__ padding, const int* __restrict__ out_len,
    float* __restrict__ out, int K)
{
    __shared__ uint4 xs[XTOT];
    const int t = threadIdx.x;
    const uint4* wsg = ws + (size_t)blockIdx.y * XTOT;

    xs[t]       = wsg[t];
    xs[t + 256] = wsg[t + 256];
    xs[t + 512] = wsg[t + 512];
    xs[t + 768] = wsg[t + 768];
    __syncthreads();

    const int lane = t & 63;
    const int ks = __builtin_amdgcn_readfirstlane(blockIdx.x * 4 + (t >> 6));

    const int dil  = dilation[ks];
    const int pd   = padding[ks];
    const int olen = out_len[ks];
    float wjf[KLEN];
    __half2 w2[KLEN];
    #pragma unroll
    for (int j = 0; j < KLEN; ++j) {
        wjf[j] = weight[ks * KLEN + j];
        w2[j] = __float2half2_rn(wjf[j]);
    }
    const __half2 bias2 = __float2half2_rn(bias[ks]);
    const __half2 zero2 = __float2half2_rn(0.0f);

    const int vbase = XPAD + lane - pd;

    __half2 acc[8][4];
    #pragma unroll
    for (int c = 0; c < 8; ++c)
        #pragma unroll
        for (int q = 0; q < 4; ++q) acc[c][q] = bias2;

    #pragma unroll
    for (int j = 0; j < KLEN; ++j) {
        if (wjf[j] != 0.0f) {                          // uniform: skip zero taps
            const uint4* xp = xs + (vbase + j * dil);  // one addr per tap
            #pragma unroll
            for (int c = 0; c < 8; ++c) {
                if (c * 64 < olen) {                   // uniform: skip dead chunks
                    const uint4 r = xp[c * 64];        // ds_read_b128, imm c*1024
                    acc[c][0] = __hfma2(w2[j], as_h2(r.x), acc[c][0]);
                    acc[c][1] = __hfma2(w2[j], as_h2(r.y), acc[c][1]);
                    acc[c][2] = __hfma2(w2[j], as_h2(r.z), acc[c][2]);
                    acc[c][3] = __hfma2(w2[j], as_h2(r.w), acc[c][3]);
                }
            }
        }
    }

    unsigned mxu[4], cfu[4];
    #pragma unroll
    for (int q = 0; q < 4; ++q) { mxu[q] = NEGINF2; cfu[q] = 0u; }

    #pragma unroll
    for (int c = 0; c < 8; ++c) {
        const int p0 = c * 64;
        if (p0 + 64 <= olen) {                         // fully-valid chunk
            #pragma unroll
            for (int q = 0; q < 4; ++q) {
                mxu[q] = pkmax_u(mxu[q], as_u(acc[c][q]));
                cfu[q] = pkadd_u(cfu[q], as_u(__hgt2(acc[c][q], zero2)));
            }
        } else if (p0 < olen) {                        // boundary chunk
            const bool vld = lane < (olen - p0);
            #pragma unroll
            for (int q = 0; q < 4; ++q) {
                const unsigned a = vld ? as_u(acc[c][q]) : NEGINF2;
                mxu[q] = pkmax_u(mxu[q], a);
                const unsigned g = vld ? as_u(__hgt2(acc[c][q], zero2)) : 0u;
                cfu[q] = pkadd_u(cfu[q], g);
            }
        }
    }

    #pragma unroll
    for (int q = 0; q < 4; ++q) {
        mxu[q] = wred_pkmax(mxu[q]);
        cfu[q] = wred_pkadd(cfu[q]);
    }

    if (lane == 0) {
        const float inv = 1.0f / (float)olen;
        const size_t row = (size_t)2 * K;
        float* o = out + (size_t)blockIdx.y * 8 * row + 2 * ks;
        #pragma unroll
        for (int q = 0; q < 4; ++q) {
            const __half2 m = as_h2(mxu[q]);
            const __half2 c = as_h2(cfu[q]);
            *(float2*)(o + (2 * q) * row)     = make_float2(__low2float(m),  __low2float(c) * inv);
            *(float2*)(o + (2 * q + 1) * row) = make_float2(__high2float(m), __high2float(c) * inv);
        }
    }
}

extern "C" void kernel_launch(void* const* d_in, const int* in_sizes, int n_in,
                              void* d_out, int out_size, void* d_ws, size_t ws_size,
                              hipStream_t stream) {
    const float* x    = (const float*)d_in[0];
    const float* w    = (const float*)d_in[1];
    const float* bias = (const float*)d_in[2];
    const int* dil    = (const int*)d_in[3];
    const int* pad    = (const int*)d_in[4];
    const int* olen   = (const int*)d_in[5];
    float* out        = (float*)d_out;

    const int K = in_sizes[2];          // 4096
    const int B = in_sizes[0] / TLEN;   // 32
    const int G = B / 8;                // 4 batch groups

    uint4* ws = (uint4*)d_ws;
    stage_ws_h<<<dim3(G * 4), 256, 0, stream>>>(x, ws);
    dim3 grid(K / 4, G);                // 1024 x 4 blocks, 4 waves each
    rf_kernel_h3<<<grid, 256, 0, stream>>>(ws, w, bias, dil, pad, olen, out, K);
    (void)n_in; (void)out_size; (void)ws_size;
}